// Round 1
// baseline (674.791 us; speedup 1.0000x reference)
//
#include <hip/hip_runtime.h>

// GCN: 4x (gcn_conv + relu) + global mean pool + linear out.
// N=100000 nodes, E=1000000 edges, G=4096 graphs, F_IN=9, H=64.
// R1: k_agg64 restructured for memory-level parallelism (wave=1 node, 4x16
//     subgroup float4 gathers, unroll x2); layer-4 agg fused with output proj.
// R2: CSR build reworked as two-pass bucketed scatter.  Old k_scatter did 1M
//     random 4B writes -> 69MB HBM writeback for a 4MB array (17x write amp,
//     75us).  Now: bucket = 128 consecutive dst nodes; bucket offsets ARE
//     row_ptr[b*128] (no extra scan); k_bin packs (src<<7)|dstoff into the
//     bucket region (line-local fills), k_csr resolves per-node order with LDS
//     cursors, one workgroup per bucket (single-writer 5KB csr regions).

static inline size_t align256(size_t x){ return (x + 255) & ~size_t(255); }

__global__ void k_zero(int* deg, float* gsum, int* gcount, int N, int G){
  int i = blockIdx.x*blockDim.x + threadIdx.x;
  if (i < N) deg[i] = 0;
  if (i < G){ gsum[i] = 0.f; gcount[i] = 0; }
}

__global__ void k_deg(const int* __restrict__ dst, const int* __restrict__ batch,
                      int* deg, int* gcount, int E, int N){
  int i = blockIdx.x*blockDim.x + threadIdx.x;
  if (i < E) atomicAdd(&deg[dst[i]], 1);
  if (i < N) atomicAdd(&gcount[batch[i]], 1);
}

__global__ void k_scanA(const int* __restrict__ deg, int* blockSums, int N){
  __shared__ int s[256];
  int t = threadIdx.x; int i = blockIdx.x*256 + t;
  s[t] = (i < N) ? deg[i] : 0;
  __syncthreads();
  for (int off=128; off>0; off>>=1){ if (t < off) s[t] += s[t+off]; __syncthreads(); }
  if (t==0) blockSums[blockIdx.x] = s[0];
}

// single-block exclusive scan of up to 512 block sums (NB=391 here)
__global__ void k_scanB(const int* __restrict__ blockSums, int* blockOffs, int NB){
  __shared__ int s[512];
  int t = threadIdx.x;
  int v = (t < NB) ? blockSums[t] : 0;
  s[t] = v; __syncthreads();
  for (int off=1; off<512; off<<=1){
    int add = (t>=off) ? s[t-off] : 0; __syncthreads();
    s[t] += add; __syncthreads();
  }
  if (t < NB) blockOffs[t] = s[t] - v;
}

// exclusive scan -> row_ptr; also init bucket cursors (bucket = 128 nodes) and dis
__global__ void k_scanC(const int* __restrict__ deg, const int* __restrict__ blockOffs,
                        int* row_ptr, int* bcursor, float* dis, int N){
  __shared__ int s[256];
  int t = threadIdx.x; int i = blockIdx.x*256 + t;
  int v = (i < N) ? deg[i] : 0;
  s[t] = v; __syncthreads();
  for (int off=1; off<256; off<<=1){
    int add = (t>=off) ? s[t-off] : 0; __syncthreads();
    s[t] += add; __syncthreads();
  }
  if (i < N){
    int row = blockOffs[blockIdx.x] + s[t] - v;   // exclusive
    row_ptr[i] = row;
    if ((i & 127) == 0) bcursor[i >> 7] = row;    // bucket base == row_ptr[b*128]
    dis[i] = rsqrtf((float)(v + 1));              // +1 self-loop; deg>=1
    if (i == N-1) row_ptr[N] = blockOffs[blockIdx.x] + s[t];
  }
}

// pass 1: scatter edges into per-bucket regions of `binned`, packed as
// (src<<7)|(dst&127).  src < 2^17 so this fits in 24 bits.
__global__ void k_bin(const int* __restrict__ src, const int* __restrict__ dst,
                      int* bcursor, int* __restrict__ binned, int E){
  int i = blockIdx.x*blockDim.x + threadIdx.x;
  if (i < E){
    int d = dst[i];
    int pos = atomicAdd(&bcursor[d >> 7], 1);
    binned[pos] = (src[i] << 7) | (d & 127);
  }
}

// pass 2: one workgroup per bucket; LDS cursors for the bucket's <=128 nodes;
// writes confined to the bucket's own ~5KB csr region.
__global__ __launch_bounds__(256) void k_csr(const int* __restrict__ binned,
                                             const int* __restrict__ row_ptr,
                                             int* __restrict__ csr, int N){
  __shared__ int lcur[128];
  int b = blockIdx.x;
  int n0 = b << 7;
  int n1 = n0 + 128; if (n1 > N) n1 = N;
  int t = threadIdx.x;
  if (t < 128 && n0 + t < n1) lcur[t] = row_ptr[n0 + t];
  __syncthreads();
  int s = row_ptr[n0], e = row_ptr[n1];
  for (int idx = s + t; idx < e; idx += 256){
    int v = binned[idx];
    int pos = atomicAdd(&lcur[v & 127], 1);
    csr[pos] = v >> 7;
  }
}

// xs[n] = x[n] * dis[n]  (premultiply so the gather loop has one load per edge)
__global__ void k_premul(const float* __restrict__ x, const float* __restrict__ dis,
                         float* __restrict__ xs, int N){
  int i = blockIdx.x*blockDim.x + threadIdx.x;
  if (i < N*9) xs[i] = x[i]*dis[i/9];
}

// layer-1 aggregation over xs (9 features): thread per (node, feature), unroll-4 MLP
__global__ void k_agg9(const float* __restrict__ xs, const float* __restrict__ dis,
                       const int* __restrict__ row_ptr, const int* __restrict__ csr,
                       float* __restrict__ xagg, int N){
  int tid = blockIdx.x*blockDim.x + threadIdx.x;
  if (tid >= N*9) return;
  int n = tid/9, f = tid - n*9;
  float dn = dis[n];
  int s0 = row_ptr[n], s1 = row_ptr[n+1];
  float a0 = xs[tid];                 // self-loop term (x[n]*dis[n])
  float a1 = 0.f, a2 = 0.f, a3 = 0.f;
  int j = s0;
  for (; j + 3 < s1; j += 4){
    int e0 = csr[j], e1 = csr[j+1], e2 = csr[j+2], e3 = csr[j+3];
    a0 += xs[e0*9+f];
    a1 += xs[e1*9+f];
    a2 += xs[e2*9+f];
    a3 += xs[e3*9+f];
  }
  for (; j < s1; j++) a0 += xs[csr[j]*9+f];
  xagg[tid] = ((a0+a1)+(a2+a3))*dn;
}

// h1 = relu(xagg @ W1 + b1)   (9 -> 64)
__global__ void k_lin1(const float* __restrict__ xagg, const float* __restrict__ W1,
                       const float* __restrict__ b1, float* __restrict__ h, int N){
  __shared__ float Wl[576];
  __shared__ float bl[64];
  int t = threadIdx.x;
  for (int i = t; i < 576; i += 256) Wl[i] = W1[i];
  if (t < 64) bl[t] = b1[t];
  __syncthreads();
  int tid = blockIdx.x*256 + t;
  int n = tid >> 6, f = tid & 63;
  if (n >= N) return;
  float acc = bl[f];
  #pragma unroll
  for (int k = 0; k < 9; k++) acc = fmaf(xagg[n*9+k], Wl[k*64+f], acc);
  h[tid] = fmaxf(acc, 0.f);
}

// m[n] = dis[n] * (h[n] @ W)   (64 -> 64); 16-node tiles, float4 outputs/thread
__global__ __launch_bounds__(256) void k_lin64(
    const float* __restrict__ h, const float* __restrict__ W,
    const float* __restrict__ dis, float* __restrict__ m, int N){
  __shared__ __align__(16) float Wl[64*64];
  __shared__ float hl[16*65];          // +1 pad: conflict-free broadcast reads
  int t = threadIdx.x;
  for (int i = t; i < 4096; i += 256) Wl[i] = W[i];
  int tiles = (N + 15) >> 4;
  int nl = t >> 4, q = t & 15;
  const float4* W4 = (const float4*)Wl;
  for (int tile = blockIdx.x; tile < tiles; tile += gridDim.x){
    int n0 = tile << 4;
    __syncthreads();
    #pragma unroll
    for (int j = 0; j < 4; j++){
      int idx = t + j*256;                       // 0..1023 over 16 nodes x 64 feats
      int node = n0 + (idx >> 6);
      float v = (node < N) ? h[n0*64 + idx] : 0.f;
      hl[(idx>>6)*65 + (idx&63)] = v;
    }
    __syncthreads();
    int node = n0 + nl;
    if (node < N){
      float4 acc = {0.f,0.f,0.f,0.f};
      #pragma unroll
      for (int k = 0; k < 64; k++){
        float hv = hl[nl*65 + k];
        float4 w = W4[k*16 + q];
        acc.x = fmaf(hv, w.x, acc.x);
        acc.y = fmaf(hv, w.y, acc.y);
        acc.z = fmaf(hv, w.z, acc.z);
        acc.w = fmaf(hv, w.w, acc.w);
      }
      float s = dis[node];
      float4 o = {acc.x*s, acc.y*s, acc.z*s, acc.w*s};
      *(float4*)&m[n0*64 + t*4] = o;
    }
  }
}

// h'[n] = relu(dis[n]*(m[n] + sum_nbr m[s]) + b)
// wave = 1 node; 4 subgroups x 16 lanes; subgroup gathers one 256B row (float4/lane);
// unroll x2 => 8 independent row-loads in flight per wave.
__global__ __launch_bounds__(256) void k_agg64(
    const float* __restrict__ m, const float* __restrict__ dis,
    const float* __restrict__ b,
    const int* __restrict__ row_ptr, const int* __restrict__ csr,
    float* __restrict__ h, int N){
  int lane = threadIdx.x & 63;
  int n = (blockIdx.x*blockDim.x + threadIdx.x) >> 6;
  if (n >= N) return;
  int sub = lane >> 4, q = lane & 15;
  const float4* m4 = (const float4*)m;
  float4 self = m4[n*16 + q];
  int s0 = row_ptr[n], s1 = row_ptr[n+1];
  float ax = 0.f, ay = 0.f, az = 0.f, aw = 0.f;
  int j = s0 + sub;
  for (; j + 4 < s1; j += 8){
    int e0 = csr[j], e1 = csr[j+4];
    float4 a = m4[e0*16 + q];
    float4 c = m4[e1*16 + q];
    ax += a.x; ay += a.y; az += a.z; aw += a.w;
    ax += c.x; ay += c.y; az += c.z; aw += c.w;
  }
  if (j < s1){
    float4 a = m4[csr[j]*16 + q];
    ax += a.x; ay += a.y; az += a.z; aw += a.w;
  }
  // combine the 4 subgroups (lane bits 4,5)
  ax += __shfl_xor(ax,16,64); ay += __shfl_xor(ay,16,64);
  az += __shfl_xor(az,16,64); aw += __shfl_xor(aw,16,64);
  ax += __shfl_xor(ax,32,64); ay += __shfl_xor(ay,32,64);
  az += __shfl_xor(az,32,64); aw += __shfl_xor(aw,32,64);
  float dn = dis[n];
  const float4* b4 = (const float4*)b;
  float4 bb = b4[q];
  float4 v;
  v.x = fmaxf(fmaf(ax + self.x, dn, bb.x), 0.f);
  v.y = fmaxf(fmaf(ay + self.y, dn, bb.y), 0.f);
  v.z = fmaxf(fmaf(az + self.z, dn, bb.z), 0.f);
  v.w = fmaxf(fmaf(aw + self.w, dn, bb.w), 0.f);
  if (sub == 0) ((float4*)h)[n*16 + q] = v;
}

// layer-4 aggregation fused with output projection: per-node dot(h4, Wout)
// -> wave reduce -> atomic segment add.  No h store at all.
__global__ __launch_bounds__(256) void k_agg64_out(
    const float* __restrict__ m, const float* __restrict__ dis,
    const float* __restrict__ b, const float* __restrict__ Wout,
    const int* __restrict__ batch,
    const int* __restrict__ row_ptr, const int* __restrict__ csr,
    float* gsum, int N){
  int lane = threadIdx.x & 63;
  int n = (blockIdx.x*blockDim.x + threadIdx.x) >> 6;
  if (n >= N) return;
  int sub = lane >> 4, q = lane & 15;
  const float4* m4 = (const float4*)m;
  float4 self = m4[n*16 + q];
  int s0 = row_ptr[n], s1 = row_ptr[n+1];
  float ax = 0.f, ay = 0.f, az = 0.f, aw = 0.f;
  int j = s0 + sub;
  for (; j + 4 < s1; j += 8){
    int e0 = csr[j], e1 = csr[j+4];
    float4 a = m4[e0*16 + q];
    float4 c = m4[e1*16 + q];
    ax += a.x; ay += a.y; az += a.z; aw += a.w;
    ax += c.x; ay += c.y; az += c.z; aw += c.w;
  }
  if (j < s1){
    float4 a = m4[csr[j]*16 + q];
    ax += a.x; ay += a.y; az += a.z; aw += a.w;
  }
  ax += __shfl_xor(ax,16,64); ay += __shfl_xor(ay,16,64);
  az += __shfl_xor(az,16,64); aw += __shfl_xor(aw,16,64);
  ax += __shfl_xor(ax,32,64); ay += __shfl_xor(ay,32,64);
  az += __shfl_xor(az,32,64); aw += __shfl_xor(aw,32,64);
  float dn = dis[n];
  const float4* b4 = (const float4*)b;
  float4 bb = b4[q];
  float4 v;
  v.x = fmaxf(fmaf(ax + self.x, dn, bb.x), 0.f);
  v.y = fmaxf(fmaf(ay + self.y, dn, bb.y), 0.f);
  v.z = fmaxf(fmaf(az + self.z, dn, bb.z), 0.f);
  v.w = fmaxf(fmaf(aw + self.w, dn, bb.w), 0.f);
  const float4* Wo4 = (const float4*)Wout;
  float4 wo = Wo4[q];
  float p = v.x*wo.x + v.y*wo.y + v.z*wo.z + v.w*wo.w;
  p += __shfl_xor(p,1,64); p += __shfl_xor(p,2,64);
  p += __shfl_xor(p,4,64); p += __shfl_xor(p,8,64);
  if (lane == 0) atomicAdd(&gsum[batch[n]], p);
}

__global__ void k_final(const float* __restrict__ gsum, const int* __restrict__ gcount,
                        const float* __restrict__ bout, float* __restrict__ out, int G){
  int g = blockIdx.x*blockDim.x + threadIdx.x;
  if (g < G){
    int c = gcount[g];
    out[g] = gsum[g]/(float)(c > 0 ? c : 1) + bout[0];
  }
}

extern "C" void kernel_launch(void* const* d_in, const int* in_sizes, int n_in,
                              void* d_out, int out_size, void* d_ws, size_t ws_size,
                              hipStream_t stream){
  const float* x    = (const float*)d_in[0];
  const int*   ei   = (const int*)d_in[1];
  const int*   batch= (const int*)d_in[2];
  const float* W1 = (const float*)d_in[3];  const float* b1 = (const float*)d_in[4];
  const float* W2 = (const float*)d_in[5];  const float* b2 = (const float*)d_in[6];
  const float* W3 = (const float*)d_in[7];  const float* b3 = (const float*)d_in[8];
  const float* W4 = (const float*)d_in[9];  const float* b4 = (const float*)d_in[10];
  const float* Wout = (const float*)d_in[11]; const float* bout = (const float*)d_in[12];
  float* out = (float*)d_out;

  const int N = in_sizes[0]/9;
  const int E = in_sizes[1]/2;
  const int G = out_size;
  const int* src = ei;        // edge_index[0]
  const int* dst = ei + E;    // edge_index[1]

  char* ws = (char*)d_ws;
  size_t off = 0;
  auto alloc = [&](size_t bytes){ void* p = ws + off; off = align256(off + bytes); return p; };
  int*   deg      = (int*)  alloc((size_t)N*4);
  int*   row_ptr  = (int*)  alloc((size_t)(N+1)*4);
  int*   csr      = (int*)  alloc((size_t)E*4);
  float* dis      = (float*)alloc((size_t)N*4);
  const int NB  = (N + 255)/256;   // 391 (< 512 required by k_scanB)
  const int NBK = (N + 127)/128;   // 782 buckets of 128 dst nodes
  int*   blockSums= (int*)  alloc((size_t)NB*4);
  int*   blockOffs= (int*)  alloc((size_t)NB*4);
  int*   bcursor  = (int*)  alloc((size_t)NBK*4);
  float* gsum     = (float*)alloc((size_t)G*4);
  int*   gcount   = (int*)  alloc((size_t)G*4);
  float* bufA     = (float*)alloc((size_t)N*64*4);
  float* bufB     = (float*)alloc((size_t)N*64*4);
  float* xagg     = bufB;   // layer-1 9-feature aggregate aliases bufB
  float* xs       = bufA;   // premultiplied x aliases bufA (freed by k_lin1 write)
  int*   binned   = (int*)bufA;  // E*4 = 4MB <= N*64*4; consumed by k_csr BEFORE
                                 // k_premul writes xs into the same region

  const int EN = (E > N) ? E : N;

  k_zero   <<<(N+255)/256, 256, 0, stream>>>(deg, gsum, gcount, N, G);
  k_deg    <<<(EN+255)/256, 256, 0, stream>>>(dst, batch, deg, gcount, E, N);
  k_scanA  <<<NB, 256, 0, stream>>>(deg, blockSums, N);
  k_scanB  <<<1, 512, 0, stream>>>(blockSums, blockOffs, NB);
  k_scanC  <<<NB, 256, 0, stream>>>(deg, blockOffs, row_ptr, bcursor, dis, N);
  k_bin    <<<(E+255)/256, 256, 0, stream>>>(src, dst, bcursor, binned, E);
  k_csr    <<<NBK, 256, 0, stream>>>(binned, row_ptr, csr, N);

  // layer 1: premultiply, aggregate (9 feats), then transform
  k_premul<<<(N*9+255)/256, 256, 0, stream>>>(x, dis, xs, N);
  k_agg9  <<<(N*9+255)/256, 256, 0, stream>>>(xs, dis, row_ptr, csr, xagg, N);
  k_lin1  <<<(N*64+255)/256, 256, 0, stream>>>(xagg, W1, b1, bufA, N);

  // layers 2-3: transform (with dis premult) then aggregate
  const float* Ws[2] = {W2, W3};
  const float* bs[2] = {b2, b3};
  for (int l = 0; l < 2; l++){
    k_lin64<<<1792, 256, 0, stream>>>(bufA, Ws[l], dis, bufB, N);
    k_agg64<<<(N*64+255)/256, 256, 0, stream>>>(bufB, dis, bs[l], row_ptr, csr, bufA, N);
  }

  // layer 4: transform, then aggregation fused with output projection + pool
  k_lin64<<<1792, 256, 0, stream>>>(bufA, W4, dis, bufB, N);
  k_agg64_out<<<(N*64+255)/256, 256, 0, stream>>>(bufB, dis, b4, Wout, batch,
                                                  row_ptr, csr, gsum, N);

  k_final<<<(G+255)/256, 256, 0, stream>>>(gsum, gcount, bout, out, G);
}

// Round 2
// 455.145 us; speedup vs baseline: 1.4826x; 1.4826x over previous
//
#include <hip/hip_runtime.h>

// GCN: 4x (gcn_conv + relu) + global mean pool + linear out.
// N=100000 nodes, E=1000000 edges, G=4096 graphs, F_IN=9, H=64.
// R1: k_agg64 restructured for memory-level parallelism (wave=1 node, 4x16
//     subgroup float4 gathers, unroll x2); layer-4 agg fused with output proj.
// R2 (FAILED, 237us): global bucket-cursor scatter -- 782-address atomic
//     contention serialized the kernel; line-level write amp persisted because
//     lines were filled at random times from random XCDs.
// R3: CSR build with NO global atomics and full-line writes only:
//     k_sortchunk: WG per 2048-edge chunk; LDS histogram over 782 buckets
//       (bucket = 128 dst nodes), LDS scan, chunk reordered bucket-major in
//       LDS, written out coalesced (+ per-chunk bucket offset row hoffC).
//     k_gather: WG per bucket; reads its segments from every chunk image
//       (scattered reads, L2-friendly), per-node order via 128 LDS cursors,
//       writes its own ~5KB csr region as a single-writer burst (amp ~1).

static inline size_t align256(size_t x){ return (x + 255) & ~size_t(255); }

#define CHUNK 2048          // edges per sort chunk
#define NBKT  782           // ceil(100000/128) buckets of 128 dst nodes

__global__ void k_zero(int* deg, float* gsum, int* gcount, int N, int G){
  int i = blockIdx.x*blockDim.x + threadIdx.x;
  if (i < N) deg[i] = 0;
  if (i < G){ gsum[i] = 0.f; gcount[i] = 0; }
}

__global__ void k_deg(const int* __restrict__ dst, const int* __restrict__ batch,
                      int* deg, int* gcount, int E, int N){
  int i = blockIdx.x*blockDim.x + threadIdx.x;
  if (i < E) atomicAdd(&deg[dst[i]], 1);
  if (i < N) atomicAdd(&gcount[batch[i]], 1);
}

__global__ void k_scanA(const int* __restrict__ deg, int* blockSums, int N){
  __shared__ int s[256];
  int t = threadIdx.x; int i = blockIdx.x*256 + t;
  s[t] = (i < N) ? deg[i] : 0;
  __syncthreads();
  for (int off=128; off>0; off>>=1){ if (t < off) s[t] += s[t+off]; __syncthreads(); }
  if (t==0) blockSums[blockIdx.x] = s[0];
}

// single-block exclusive scan of up to 512 block sums (NB=391 here)
__global__ void k_scanB(const int* __restrict__ blockSums, int* blockOffs, int NB){
  __shared__ int s[512];
  int t = threadIdx.x;
  int v = (t < NB) ? blockSums[t] : 0;
  s[t] = v; __syncthreads();
  for (int off=1; off<512; off<<=1){
    int add = (t>=off) ? s[t-off] : 0; __syncthreads();
    s[t] += add; __syncthreads();
  }
  if (t < NB) blockOffs[t] = s[t] - v;
}

// exclusive scan -> row_ptr; also dis
__global__ void k_scanC(const int* __restrict__ deg, const int* __restrict__ blockOffs,
                        int* row_ptr, float* dis, int N){
  __shared__ int s[256];
  int t = threadIdx.x; int i = blockIdx.x*256 + t;
  int v = (i < N) ? deg[i] : 0;
  s[t] = v; __syncthreads();
  for (int off=1; off<256; off<<=1){
    int add = (t>=off) ? s[t-off] : 0; __syncthreads();
    s[t] += add; __syncthreads();
  }
  if (i < N){
    int row = blockOffs[blockIdx.x] + s[t] - v;   // exclusive
    row_ptr[i] = row;
    dis[i] = rsqrtf((float)(v + 1));              // +1 self-loop; deg>=1
    if (i == N-1) row_ptr[N] = blockOffs[blockIdx.x] + s[t];
  }
}

// pass 1: sort a 2048-edge chunk by bucket entirely in LDS, emit the sorted
// image (coalesced) + the chunk's 783-entry bucket-offset row (coalesced).
// Entry packed as (src<<7)|(dst&127); src < 2^17 fits.
__global__ __launch_bounds__(256) void k_sortchunk(
    const int* __restrict__ src, const int* __restrict__ dst,
    int* __restrict__ binned, int* __restrict__ hoffC, int E){
  __shared__ int hcnt[1024];            // 782 used; padded pow2 for scan
  __shared__ int simg[CHUNK];
  int c = blockIdx.x, t = threadIdx.x;
  int e0 = c*CHUNK;
  int cnt = E - e0; if (cnt > CHUNK) cnt = CHUNK;

  for (int i = t; i < 1024; i += 256) hcnt[i] = 0;
  __syncthreads();

  int b_[8], r_[8], v_[8];              // static-indexed (stays in VGPRs)
  #pragma unroll
  for (int j = 0; j < 8; j++){
    int i = t + j*256;
    if (i < cnt){
      int d = dst[e0+i];
      int s = src[e0+i];
      int b = d >> 7;
      b_[j] = b;
      r_[j] = atomicAdd(&hcnt[b], 1);
      v_[j] = (s << 7) | (d & 127);
    } else b_[j] = -1;
  }
  __syncthreads();

  // in-place Hillis-Steele inclusive scan of hcnt[0..1023]
  int own[4];
  #pragma unroll
  for (int j = 0; j < 4; j++) own[j] = hcnt[t + j*256];
  for (int off = 1; off < 1024; off <<= 1){
    int nv[4];
    #pragma unroll
    for (int j = 0; j < 4; j++){
      int i = t + j*256;
      nv[j] = hcnt[i] + ((i >= off) ? hcnt[i-off] : 0);
    }
    __syncthreads();
    #pragma unroll
    for (int j = 0; j < 4; j++) hcnt[t + j*256] = nv[j];
    __syncthreads();
  }
  // inclusive -> exclusive
  #pragma unroll
  for (int j = 0; j < 4; j++) hcnt[t + j*256] -= own[j];
  __syncthreads();

  // emit bucket-offset row (hcnt[782] == cnt since buckets >=782 are empty)
  for (int i = t; i < 783; i += 256) hoffC[c*783 + i] = hcnt[i];

  // place edges bucket-major in LDS
  #pragma unroll
  for (int j = 0; j < 8; j++)
    if (b_[j] >= 0) simg[hcnt[b_[j]] + r_[j]] = v_[j];
  __syncthreads();

  // coalesced stream-out of the sorted chunk image
  for (int i = t; i < cnt; i += 256) binned[e0 + i] = simg[i];
}

// pass 2: WG per bucket gathers its segments from every chunk image and writes
// its own csr region (single-writer, full-line writebacks).  Per-node order
// resolved with LDS cursors (fuses the old k_csr).
__global__ __launch_bounds__(256) void k_gather(
    const int* __restrict__ binned, const int* __restrict__ hoffC,
    const int* __restrict__ row_ptr,
    int* __restrict__ csr, int N, int NC){
  __shared__ int lcur[128];
  int b = blockIdx.x, t = threadIdx.x;
  int n0 = b << 7;
  int nn = N - n0; if (nn > 128) nn = 128;
  if (t < nn) lcur[t] = row_ptr[n0 + t];
  __syncthreads();
  for (int c = t; c < NC; c += 256){
    int o0 = hoffC[c*783 + b];
    int o1 = hoffC[c*783 + b + 1];
    int base = c*CHUNK;
    for (int k = o0; k < o1; k++){
      int v = binned[base + k];
      int pos = atomicAdd(&lcur[v & 127], 1);
      csr[pos] = v >> 7;
    }
  }
}

// xs[n] = x[n] * dis[n]  (premultiply so the gather loop has one load per edge)
__global__ void k_premul(const float* __restrict__ x, const float* __restrict__ dis,
                         float* __restrict__ xs, int N){
  int i = blockIdx.x*blockDim.x + threadIdx.x;
  if (i < N*9) xs[i] = x[i]*dis[i/9];
}

// layer-1 aggregation over xs (9 features): thread per (node, feature), unroll-4 MLP
__global__ void k_agg9(const float* __restrict__ xs, const float* __restrict__ dis,
                       const int* __restrict__ row_ptr, const int* __restrict__ csr,
                       float* __restrict__ xagg, int N){
  int tid = blockIdx.x*blockDim.x + threadIdx.x;
  if (tid >= N*9) return;
  int n = tid/9, f = tid - n*9;
  float dn = dis[n];
  int s0 = row_ptr[n], s1 = row_ptr[n+1];
  float a0 = xs[tid];                 // self-loop term (x[n]*dis[n])
  float a1 = 0.f, a2 = 0.f, a3 = 0.f;
  int j = s0;
  for (; j + 3 < s1; j += 4){
    int e0 = csr[j], e1 = csr[j+1], e2 = csr[j+2], e3 = csr[j+3];
    a0 += xs[e0*9+f];
    a1 += xs[e1*9+f];
    a2 += xs[e2*9+f];
    a3 += xs[e3*9+f];
  }
  for (; j < s1; j++) a0 += xs[csr[j]*9+f];
  xagg[tid] = ((a0+a1)+(a2+a3))*dn;
}

// h1 = relu(xagg @ W1 + b1)   (9 -> 64)
__global__ void k_lin1(const float* __restrict__ xagg, const float* __restrict__ W1,
                       const float* __restrict__ b1, float* __restrict__ h, int N){
  __shared__ float Wl[576];
  __shared__ float bl[64];
  int t = threadIdx.x;
  for (int i = t; i < 576; i += 256) Wl[i] = W1[i];
  if (t < 64) bl[t] = b1[t];
  __syncthreads();
  int tid = blockIdx.x*256 + t;
  int n = tid >> 6, f = tid & 63;
  if (n >= N) return;
  float acc = bl[f];
  #pragma unroll
  for (int k = 0; k < 9; k++) acc = fmaf(xagg[n*9+k], Wl[k*64+f], acc);
  h[tid] = fmaxf(acc, 0.f);
}

// m[n] = dis[n] * (h[n] @ W)   (64 -> 64); 16-node tiles, float4 outputs/thread
__global__ __launch_bounds__(256) void k_lin64(
    const float* __restrict__ h, const float* __restrict__ W,
    const float* __restrict__ dis, float* __restrict__ m, int N){
  __shared__ __align__(16) float Wl[64*64];
  __shared__ float hl[16*65];          // +1 pad: conflict-free broadcast reads
  int t = threadIdx.x;
  for (int i = t; i < 4096; i += 256) Wl[i] = W[i];
  int tiles = (N + 15) >> 4;
  int nl = t >> 4, q = t & 15;
  const float4* W4 = (const float4*)Wl;
  for (int tile = blockIdx.x; tile < tiles; tile += gridDim.x){
    int n0 = tile << 4;
    __syncthreads();
    #pragma unroll
    for (int j = 0; j < 4; j++){
      int idx = t + j*256;                       // 0..1023 over 16 nodes x 64 feats
      int node = n0 + (idx >> 6);
      float v = (node < N) ? h[n0*64 + idx] : 0.f;
      hl[(idx>>6)*65 + (idx&63)] = v;
    }
    __syncthreads();
    int node = n0 + nl;
    if (node < N){
      float4 acc = {0.f,0.f,0.f,0.f};
      #pragma unroll
      for (int k = 0; k < 64; k++){
        float hv = hl[nl*65 + k];
        float4 w = W4[k*16 + q];
        acc.x = fmaf(hv, w.x, acc.x);
        acc.y = fmaf(hv, w.y, acc.y);
        acc.z = fmaf(hv, w.z, acc.z);
        acc.w = fmaf(hv, w.w, acc.w);
      }
      float s = dis[node];
      float4 o = {acc.x*s, acc.y*s, acc.z*s, acc.w*s};
      *(float4*)&m[n0*64 + t*4] = o;
    }
  }
}

// h'[n] = relu(dis[n]*(m[n] + sum_nbr m[s]) + b)
// wave = 1 node; 4 subgroups x 16 lanes; subgroup gathers one 256B row (float4/lane);
// unroll x2 => 8 independent row-loads in flight per wave.
__global__ __launch_bounds__(256) void k_agg64(
    const float* __restrict__ m, const float* __restrict__ dis,
    const float* __restrict__ b,
    const int* __restrict__ row_ptr, const int* __restrict__ csr,
    float* __restrict__ h, int N){
  int lane = threadIdx.x & 63;
  int n = (blockIdx.x*blockDim.x + threadIdx.x) >> 6;
  if (n >= N) return;
  int sub = lane >> 4, q = lane & 15;
  const float4* m4 = (const float4*)m;
  float4 self = m4[n*16 + q];
  int s0 = row_ptr[n], s1 = row_ptr[n+1];
  float ax = 0.f, ay = 0.f, az = 0.f, aw = 0.f;
  int j = s0 + sub;
  for (; j + 4 < s1; j += 8){
    int e0 = csr[j], e1 = csr[j+4];
    float4 a = m4[e0*16 + q];
    float4 c = m4[e1*16 + q];
    ax += a.x; ay += a.y; az += a.z; aw += a.w;
    ax += c.x; ay += c.y; az += c.z; aw += c.w;
  }
  if (j < s1){
    float4 a = m4[csr[j]*16 + q];
    ax += a.x; ay += a.y; az += a.z; aw += a.w;
  }
  // combine the 4 subgroups (lane bits 4,5)
  ax += __shfl_xor(ax,16,64); ay += __shfl_xor(ay,16,64);
  az += __shfl_xor(az,16,64); aw += __shfl_xor(aw,16,64);
  ax += __shfl_xor(ax,32,64); ay += __shfl_xor(ay,32,64);
  az += __shfl_xor(az,32,64); aw += __shfl_xor(aw,32,64);
  float dn = dis[n];
  const float4* b4 = (const float4*)b;
  float4 bb = b4[q];
  float4 v;
  v.x = fmaxf(fmaf(ax + self.x, dn, bb.x), 0.f);
  v.y = fmaxf(fmaf(ay + self.y, dn, bb.y), 0.f);
  v.z = fmaxf(fmaf(az + self.z, dn, bb.z), 0.f);
  v.w = fmaxf(fmaf(aw + self.w, dn, bb.w), 0.f);
  if (sub == 0) ((float4*)h)[n*16 + q] = v;
}

// layer-4 aggregation fused with output projection: per-node dot(h4, Wout)
// -> wave reduce -> atomic segment add.  No h store at all.
__global__ __launch_bounds__(256) void k_agg64_out(
    const float* __restrict__ m, const float* __restrict__ dis,
    const float* __restrict__ b, const float* __restrict__ Wout,
    const int* __restrict__ batch,
    const int* __restrict__ row_ptr, const int* __restrict__ csr,
    float* gsum, int N){
  int lane = threadIdx.x & 63;
  int n = (blockIdx.x*blockDim.x + threadIdx.x) >> 6;
  if (n >= N) return;
  int sub = lane >> 4, q = lane & 15;
  const float4* m4 = (const float4*)m;
  float4 self = m4[n*16 + q];
  int s0 = row_ptr[n], s1 = row_ptr[n+1];
  float ax = 0.f, ay = 0.f, az = 0.f, aw = 0.f;
  int j = s0 + sub;
  for (; j + 4 < s1; j += 8){
    int e0 = csr[j], e1 = csr[j+4];
    float4 a = m4[e0*16 + q];
    float4 c = m4[e1*16 + q];
    ax += a.x; ay += a.y; az += a.z; aw += a.w;
    ax += c.x; ay += c.y; az += c.z; aw += c.w;
  }
  if (j < s1){
    float4 a = m4[csr[j]*16 + q];
    ax += a.x; ay += a.y; az += a.z; aw += a.w;
  }
  ax += __shfl_xor(ax,16,64); ay += __shfl_xor(ay,16,64);
  az += __shfl_xor(az,16,64); aw += __shfl_xor(aw,16,64);
  ax += __shfl_xor(ax,32,64); ay += __shfl_xor(ay,32,64);
  az += __shfl_xor(az,32,64); aw += __shfl_xor(aw,32,64);
  float dn = dis[n];
  const float4* b4 = (const float4*)b;
  float4 bb = b4[q];
  float4 v;
  v.x = fmaxf(fmaf(ax + self.x, dn, bb.x), 0.f);
  v.y = fmaxf(fmaf(ay + self.y, dn, bb.y), 0.f);
  v.z = fmaxf(fmaf(az + self.z, dn, bb.z), 0.f);
  v.w = fmaxf(fmaf(aw + self.w, dn, bb.w), 0.f);
  const float4* Wo4 = (const float4*)Wout;
  float4 wo = Wo4[q];
  float p = v.x*wo.x + v.y*wo.y + v.z*wo.z + v.w*wo.w;
  p += __shfl_xor(p,1,64); p += __shfl_xor(p,2,64);
  p += __shfl_xor(p,4,64); p += __shfl_xor(p,8,64);
  if (lane == 0) atomicAdd(&gsum[batch[n]], p);
}

__global__ void k_final(const float* __restrict__ gsum, const int* __restrict__ gcount,
                        const float* __restrict__ bout, float* __restrict__ out, int G){
  int g = blockIdx.x*blockDim.x + threadIdx.x;
  if (g < G){
    int c = gcount[g];
    out[g] = gsum[g]/(float)(c > 0 ? c : 1) + bout[0];
  }
}

extern "C" void kernel_launch(void* const* d_in, const int* in_sizes, int n_in,
                              void* d_out, int out_size, void* d_ws, size_t ws_size,
                              hipStream_t stream){
  const float* x    = (const float*)d_in[0];
  const int*   ei   = (const int*)d_in[1];
  const int*   batch= (const int*)d_in[2];
  const float* W1 = (const float*)d_in[3];  const float* b1 = (const float*)d_in[4];
  const float* W2 = (const float*)d_in[5];  const float* b2 = (const float*)d_in[6];
  const float* W3 = (const float*)d_in[7];  const float* b3 = (const float*)d_in[8];
  const float* W4 = (const float*)d_in[9];  const float* b4 = (const float*)d_in[10];
  const float* Wout = (const float*)d_in[11]; const float* bout = (const float*)d_in[12];
  float* out = (float*)d_out;

  const int N = in_sizes[0]/9;
  const int E = in_sizes[1]/2;
  const int G = out_size;
  const int* src = ei;        // edge_index[0]
  const int* dst = ei + E;    // edge_index[1]

  char* ws = (char*)d_ws;
  size_t off = 0;
  auto alloc = [&](size_t bytes){ void* p = ws + off; off = align256(off + bytes); return p; };
  int*   deg      = (int*)  alloc((size_t)N*4);
  int*   row_ptr  = (int*)  alloc((size_t)(N+1)*4);
  int*   csr      = (int*)  alloc((size_t)E*4);
  float* dis      = (float*)alloc((size_t)N*4);
  const int NB  = (N + 255)/256;        // 391 (< 512 required by k_scanB)
  const int NBK = (N + 127)/128;        // 782 buckets of 128 dst nodes
  const int NC  = (E + CHUNK-1)/CHUNK;  // 489 sort chunks
  int*   blockSums= (int*)  alloc((size_t)NB*4);
  int*   blockOffs= (int*)  alloc((size_t)NB*4);
  int*   hoffC    = (int*)  alloc((size_t)NC*783*4);   // per-chunk bucket offsets
  float* gsum     = (float*)alloc((size_t)G*4);
  int*   gcount   = (int*)  alloc((size_t)G*4);
  float* bufA     = (float*)alloc((size_t)N*64*4);
  float* bufB     = (float*)alloc((size_t)N*64*4);
  float* xagg     = bufB;   // layer-1 9-feature aggregate aliases bufB
  float* xs       = bufA;   // premultiplied x aliases bufA (freed by k_lin1 write)
  int*   binned   = (int*)bufA;  // E*4 = 4MB <= N*64*4; consumed by k_gather
                                 // BEFORE k_premul writes xs into the same region

  const int EN = (E > N) ? E : N;

  k_zero     <<<(N+255)/256, 256, 0, stream>>>(deg, gsum, gcount, N, G);
  k_deg      <<<(EN+255)/256, 256, 0, stream>>>(dst, batch, deg, gcount, E, N);
  k_scanA    <<<NB, 256, 0, stream>>>(deg, blockSums, N);
  k_scanB    <<<1, 512, 0, stream>>>(blockSums, blockOffs, NB);
  k_scanC    <<<NB, 256, 0, stream>>>(deg, blockOffs, row_ptr, dis, N);
  k_sortchunk<<<NC, 256, 0, stream>>>(src, dst, binned, hoffC, E);
  k_gather   <<<NBK, 256, 0, stream>>>(binned, hoffC, row_ptr, csr, N, NC);

  // layer 1: premultiply, aggregate (9 feats), then transform
  k_premul<<<(N*9+255)/256, 256, 0, stream>>>(x, dis, xs, N);
  k_agg9  <<<(N*9+255)/256, 256, 0, stream>>>(xs, dis, row_ptr, csr, xagg, N);
  k_lin1  <<<(N*64+255)/256, 256, 0, stream>>>(xagg, W1, b1, bufA, N);

  // layers 2-3: transform (with dis premult) then aggregate
  const float* Ws[2] = {W2, W3};
  const float* bs[2] = {b2, b3};
  for (int l = 0; l < 2; l++){
    k_lin64<<<1792, 256, 0, stream>>>(bufA, Ws[l], dis, bufB, N);
    k_agg64<<<(N*64+255)/256, 256, 0, stream>>>(bufB, dis, bs[l], row_ptr, csr, bufA, N);
  }

  // layer 4: transform, then aggregation fused with output projection + pool
  k_lin64<<<1792, 256, 0, stream>>>(bufA, W4, dis, bufB, N);
  k_agg64_out<<<(N*64+255)/256, 256, 0, stream>>>(bufB, dis, b4, Wout, batch,
                                                  row_ptr, csr, gsum, N);

  k_final<<<(G+255)/256, 256, 0, stream>>>(gsum, gcount, bout, out, G);
}

// Round 3
// 435.698 us; speedup vs baseline: 1.5488x; 1.0446x over previous
//
#include <hip/hip_runtime.h>
#include <hip/hip_fp16.h>

// GCN: 4x (gcn_conv + relu) + global mean pool + linear out.
// N=100000 nodes, E=1000000 edges, G=4096 graphs, F_IN=9, H=64.
// R1: k_agg64 restructured for memory-level parallelism (wave=1 node, 4x16
//     subgroup float4 gathers, unroll x2); layer-4 agg fused with output proj.
// R2 (FAILED, 237us): global bucket-cursor scatter -- atomic contention.
// R3: scatter-free CSR build (LDS chunk sort + single-writer bucket gather).
//     Profile now: 3x k_agg64* at 75us each, latency-bound on random 256B row
//     gathers from a 25.6MB footprint (3.8 TB/s delivered, no pipe saturated).
// R4: message rows m[] stored as fp16 (128B/row, footprint 12.8MB).  Random
//     graph => no locality to mine; the only lever on a concurrency-limited
//     gather is bytes/edge.  h, accumulation, weights, layer-1 stay fp32; only
//     m is rounded (3x per forward).  Expect agg64 75->~45us, total ~350us.

static inline size_t align256(size_t x){ return (x + 255) & ~size_t(255); }

#define CHUNK 2048          // edges per sort chunk
#define NBKT  782           // ceil(100000/128) buckets of 128 dst nodes

struct __align__(8) h4v { __half2 a, b; };   // 4 halves = 8B

__global__ void k_zero(int* deg, float* gsum, int* gcount, int N, int G){
  int i = blockIdx.x*blockDim.x + threadIdx.x;
  if (i < N) deg[i] = 0;
  if (i < G){ gsum[i] = 0.f; gcount[i] = 0; }
}

__global__ void k_deg(const int* __restrict__ dst, const int* __restrict__ batch,
                      int* deg, int* gcount, int E, int N){
  int i = blockIdx.x*blockDim.x + threadIdx.x;
  if (i < E) atomicAdd(&deg[dst[i]], 1);
  if (i < N) atomicAdd(&gcount[batch[i]], 1);
}

__global__ void k_scanA(const int* __restrict__ deg, int* blockSums, int N){
  __shared__ int s[256];
  int t = threadIdx.x; int i = blockIdx.x*256 + t;
  s[t] = (i < N) ? deg[i] : 0;
  __syncthreads();
  for (int off=128; off>0; off>>=1){ if (t < off) s[t] += s[t+off]; __syncthreads(); }
  if (t==0) blockSums[blockIdx.x] = s[0];
}

// single-block exclusive scan of up to 512 block sums (NB=391 here)
__global__ void k_scanB(const int* __restrict__ blockSums, int* blockOffs, int NB){
  __shared__ int s[512];
  int t = threadIdx.x;
  int v = (t < NB) ? blockSums[t] : 0;
  s[t] = v; __syncthreads();
  for (int off=1; off<512; off<<=1){
    int add = (t>=off) ? s[t-off] : 0; __syncthreads();
    s[t] += add; __syncthreads();
  }
  if (t < NB) blockOffs[t] = s[t] - v;
}

// exclusive scan -> row_ptr; also dis
__global__ void k_scanC(const int* __restrict__ deg, const int* __restrict__ blockOffs,
                        int* row_ptr, float* dis, int N){
  __shared__ int s[256];
  int t = threadIdx.x; int i = blockIdx.x*256 + t;
  int v = (i < N) ? deg[i] : 0;
  s[t] = v; __syncthreads();
  for (int off=1; off<256; off<<=1){
    int add = (t>=off) ? s[t-off] : 0; __syncthreads();
    s[t] += add; __syncthreads();
  }
  if (i < N){
    int row = blockOffs[blockIdx.x] + s[t] - v;   // exclusive
    row_ptr[i] = row;
    dis[i] = rsqrtf((float)(v + 1));              // +1 self-loop; deg>=1
    if (i == N-1) row_ptr[N] = blockOffs[blockIdx.x] + s[t];
  }
}

// pass 1: sort a 2048-edge chunk by bucket entirely in LDS, emit the sorted
// image (coalesced) + the chunk's 783-entry bucket-offset row (coalesced).
// Entry packed as (src<<7)|(dst&127); src < 2^17 fits.
__global__ __launch_bounds__(256) void k_sortchunk(
    const int* __restrict__ src, const int* __restrict__ dst,
    int* __restrict__ binned, int* __restrict__ hoffC, int E){
  __shared__ int hcnt[1024];            // 782 used; padded pow2 for scan
  __shared__ int simg[CHUNK];
  int c = blockIdx.x, t = threadIdx.x;
  int e0 = c*CHUNK;
  int cnt = E - e0; if (cnt > CHUNK) cnt = CHUNK;

  for (int i = t; i < 1024; i += 256) hcnt[i] = 0;
  __syncthreads();

  int b_[8], r_[8], v_[8];              // static-indexed (stays in VGPRs)
  #pragma unroll
  for (int j = 0; j < 8; j++){
    int i = t + j*256;
    if (i < cnt){
      int d = dst[e0+i];
      int s = src[e0+i];
      int b = d >> 7;
      b_[j] = b;
      r_[j] = atomicAdd(&hcnt[b], 1);
      v_[j] = (s << 7) | (d & 127);
    } else b_[j] = -1;
  }
  __syncthreads();

  // in-place Hillis-Steele inclusive scan of hcnt[0..1023]
  int own[4];
  #pragma unroll
  for (int j = 0; j < 4; j++) own[j] = hcnt[t + j*256];
  for (int off = 1; off < 1024; off <<= 1){
    int nv[4];
    #pragma unroll
    for (int j = 0; j < 4; j++){
      int i = t + j*256;
      nv[j] = hcnt[i] + ((i >= off) ? hcnt[i-off] : 0);
    }
    __syncthreads();
    #pragma unroll
    for (int j = 0; j < 4; j++) hcnt[t + j*256] = nv[j];
    __syncthreads();
  }
  // inclusive -> exclusive
  #pragma unroll
  for (int j = 0; j < 4; j++) hcnt[t + j*256] -= own[j];
  __syncthreads();

  // emit bucket-offset row (hcnt[782] == cnt since buckets >=782 are empty)
  for (int i = t; i < 783; i += 256) hoffC[c*783 + i] = hcnt[i];

  // place edges bucket-major in LDS
  #pragma unroll
  for (int j = 0; j < 8; j++)
    if (b_[j] >= 0) simg[hcnt[b_[j]] + r_[j]] = v_[j];
  __syncthreads();

  // coalesced stream-out of the sorted chunk image
  for (int i = t; i < cnt; i += 256) binned[e0 + i] = simg[i];
}

// pass 2: WG per bucket gathers its segments from every chunk image and writes
// its own csr region (single-writer, full-line writebacks).  Per-node order
// resolved with LDS cursors.
__global__ __launch_bounds__(256) void k_gather(
    const int* __restrict__ binned, const int* __restrict__ hoffC,
    const int* __restrict__ row_ptr,
    int* __restrict__ csr, int N, int NC){
  __shared__ int lcur[128];
  int b = blockIdx.x, t = threadIdx.x;
  int n0 = b << 7;
  int nn = N - n0; if (nn > 128) nn = 128;
  if (t < nn) lcur[t] = row_ptr[n0 + t];
  __syncthreads();
  for (int c = t; c < NC; c += 256){
    int o0 = hoffC[c*783 + b];
    int o1 = hoffC[c*783 + b + 1];
    int base = c*CHUNK;
    for (int k = o0; k < o1; k++){
      int v = binned[base + k];
      int pos = atomicAdd(&lcur[v & 127], 1);
      csr[pos] = v >> 7;
    }
  }
}

// xs[n] = x[n] * dis[n]  (premultiply so the gather loop has one load per edge)
__global__ void k_premul(const float* __restrict__ x, const float* __restrict__ dis,
                         float* __restrict__ xs, int N){
  int i = blockIdx.x*blockDim.x + threadIdx.x;
  if (i < N*9) xs[i] = x[i]*dis[i/9];
}

// layer-1 aggregation over xs (9 features): thread per (node, feature), unroll-4 MLP
__global__ void k_agg9(const float* __restrict__ xs, const float* __restrict__ dis,
                       const int* __restrict__ row_ptr, const int* __restrict__ csr,
                       float* __restrict__ xagg, int N){
  int tid = blockIdx.x*blockDim.x + threadIdx.x;
  if (tid >= N*9) return;
  int n = tid/9, f = tid - n*9;
  float dn = dis[n];
  int s0 = row_ptr[n], s1 = row_ptr[n+1];
  float a0 = xs[tid];                 // self-loop term (x[n]*dis[n])
  float a1 = 0.f, a2 = 0.f, a3 = 0.f;
  int j = s0;
  for (; j + 3 < s1; j += 4){
    int e0 = csr[j], e1 = csr[j+1], e2 = csr[j+2], e3 = csr[j+3];
    a0 += xs[e0*9+f];
    a1 += xs[e1*9+f];
    a2 += xs[e2*9+f];
    a3 += xs[e3*9+f];
  }
  for (; j < s1; j++) a0 += xs[csr[j]*9+f];
  xagg[tid] = ((a0+a1)+(a2+a3))*dn;
}

// h1 = relu(xagg @ W1 + b1)   (9 -> 64)
__global__ void k_lin1(const float* __restrict__ xagg, const float* __restrict__ W1,
                       const float* __restrict__ b1, float* __restrict__ h, int N){
  __shared__ float Wl[576];
  __shared__ float bl[64];
  int t = threadIdx.x;
  for (int i = t; i < 576; i += 256) Wl[i] = W1[i];
  if (t < 64) bl[t] = b1[t];
  __syncthreads();
  int tid = blockIdx.x*256 + t;
  int n = tid >> 6, f = tid & 63;
  if (n >= N) return;
  float acc = bl[f];
  #pragma unroll
  for (int k = 0; k < 9; k++) acc = fmaf(xagg[n*9+k], Wl[k*64+f], acc);
  h[tid] = fmaxf(acc, 0.f);
}

// m[n] = fp16( dis[n] * (h[n] @ W) )   (64 -> 64); 16-node tiles, 4 outs/thread
__global__ __launch_bounds__(256) void k_lin64(
    const float* __restrict__ h, const float* __restrict__ W,
    const float* __restrict__ dis, h4v* __restrict__ m, int N){
  __shared__ __align__(16) float Wl[64*64];
  __shared__ float hl[16*65];          // +1 pad: conflict-free broadcast reads
  int t = threadIdx.x;
  for (int i = t; i < 4096; i += 256) Wl[i] = W[i];
  int tiles = (N + 15) >> 4;
  int nl = t >> 4, q = t & 15;
  const float4* W4 = (const float4*)Wl;
  for (int tile = blockIdx.x; tile < tiles; tile += gridDim.x){
    int n0 = tile << 4;
    __syncthreads();
    #pragma unroll
    for (int j = 0; j < 4; j++){
      int idx = t + j*256;                       // 0..1023 over 16 nodes x 64 feats
      int node = n0 + (idx >> 6);
      float v = (node < N) ? h[n0*64 + idx] : 0.f;
      hl[(idx>>6)*65 + (idx&63)] = v;
    }
    __syncthreads();
    int node = n0 + nl;
    if (node < N){
      float4 acc = {0.f,0.f,0.f,0.f};
      #pragma unroll
      for (int k = 0; k < 64; k++){
        float hv = hl[nl*65 + k];
        float4 w = W4[k*16 + q];
        acc.x = fmaf(hv, w.x, acc.x);
        acc.y = fmaf(hv, w.y, acc.y);
        acc.z = fmaf(hv, w.z, acc.z);
        acc.w = fmaf(hv, w.w, acc.w);
      }
      float s = dis[node];
      h4v o;
      o.a = __floats2half2_rn(acc.x*s, acc.y*s);
      o.b = __floats2half2_rn(acc.z*s, acc.w*s);
      m[n0*16 + t] = o;                 // 8B/thread, coalesced
    }
  }
}

// h'[n] = relu(dis[n]*(m[n] + sum_nbr m[s]) + b)
// wave = 1 node; 4 subgroups x 16 lanes; subgroup gathers one 128B fp16 row
// (8B/lane); unroll x2 => multiple independent row-loads in flight per wave.
__global__ __launch_bounds__(256) void k_agg64(
    const h4v* __restrict__ m, const float* __restrict__ dis,
    const float* __restrict__ b,
    const int* __restrict__ row_ptr, const int* __restrict__ csr,
    float* __restrict__ h, int N){
  int lane = threadIdx.x & 63;
  int n = (blockIdx.x*blockDim.x + threadIdx.x) >> 6;
  if (n >= N) return;
  int sub = lane >> 4, q = lane & 15;
  h4v sf = m[n*16 + q];
  float2 s01 = __half22float2(sf.a), s23 = __half22float2(sf.b);
  int s0 = row_ptr[n], s1 = row_ptr[n+1];
  float ax = 0.f, ay = 0.f, az = 0.f, aw = 0.f;
  int j = s0 + sub;
  for (; j + 4 < s1; j += 8){
    int e0 = csr[j], e1 = csr[j+4];
    h4v a = m[e0*16 + q];
    h4v c = m[e1*16 + q];
    float2 a01 = __half22float2(a.a), a23 = __half22float2(a.b);
    float2 c01 = __half22float2(c.a), c23 = __half22float2(c.b);
    ax += a01.x; ay += a01.y; az += a23.x; aw += a23.y;
    ax += c01.x; ay += c01.y; az += c23.x; aw += c23.y;
  }
  if (j < s1){
    h4v a = m[csr[j]*16 + q];
    float2 a01 = __half22float2(a.a), a23 = __half22float2(a.b);
    ax += a01.x; ay += a01.y; az += a23.x; aw += a23.y;
  }
  // combine the 4 subgroups (lane bits 4,5)
  ax += __shfl_xor(ax,16,64); ay += __shfl_xor(ay,16,64);
  az += __shfl_xor(az,16,64); aw += __shfl_xor(aw,16,64);
  ax += __shfl_xor(ax,32,64); ay += __shfl_xor(ay,32,64);
  az += __shfl_xor(az,32,64); aw += __shfl_xor(aw,32,64);
  float dn = dis[n];
  const float4* b4 = (const float4*)b;
  float4 bb = b4[q];
  float4 v;
  v.x = fmaxf(fmaf(ax + s01.x, dn, bb.x), 0.f);
  v.y = fmaxf(fmaf(ay + s01.y, dn, bb.y), 0.f);
  v.z = fmaxf(fmaf(az + s23.x, dn, bb.z), 0.f);
  v.w = fmaxf(fmaf(aw + s23.y, dn, bb.w), 0.f);
  if (sub == 0) ((float4*)h)[n*16 + q] = v;
}

// layer-4 aggregation fused with output projection: per-node dot(h4, Wout)
// -> wave reduce -> atomic segment add.  No h store at all.
__global__ __launch_bounds__(256) void k_agg64_out(
    const h4v* __restrict__ m, const float* __restrict__ dis,
    const float* __restrict__ b, const float* __restrict__ Wout,
    const int* __restrict__ batch,
    const int* __restrict__ row_ptr, const int* __restrict__ csr,
    float* gsum, int N){
  int lane = threadIdx.x & 63;
  int n = (blockIdx.x*blockDim.x + threadIdx.x) >> 6;
  if (n >= N) return;
  int sub = lane >> 4, q = lane & 15;
  h4v sf = m[n*16 + q];
  float2 s01 = __half22float2(sf.a), s23 = __half22float2(sf.b);
  int s0 = row_ptr[n], s1 = row_ptr[n+1];
  float ax = 0.f, ay = 0.f, az = 0.f, aw = 0.f;
  int j = s0 + sub;
  for (; j + 4 < s1; j += 8){
    int e0 = csr[j], e1 = csr[j+4];
    h4v a = m[e0*16 + q];
    h4v c = m[e1*16 + q];
    float2 a01 = __half22float2(a.a), a23 = __half22float2(a.b);
    float2 c01 = __half22float2(c.a), c23 = __half22float2(c.b);
    ax += a01.x; ay += a01.y; az += a23.x; aw += a23.y;
    ax += c01.x; ay += c01.y; az += c23.x; aw += c23.y;
  }
  if (j < s1){
    h4v a = m[csr[j]*16 + q];
    float2 a01 = __half22float2(a.a), a23 = __half22float2(a.b);
    ax += a01.x; ay += a01.y; az += a23.x; aw += a23.y;
  }
  ax += __shfl_xor(ax,16,64); ay += __shfl_xor(ay,16,64);
  az += __shfl_xor(az,16,64); aw += __shfl_xor(aw,16,64);
  ax += __shfl_xor(ax,32,64); ay += __shfl_xor(ay,32,64);
  az += __shfl_xor(az,32,64); aw += __shfl_xor(aw,32,64);
  float dn = dis[n];
  const float4* b4 = (const float4*)b;
  float4 bb = b4[q];
  float4 v;
  v.x = fmaxf(fmaf(ax + s01.x, dn, bb.x), 0.f);
  v.y = fmaxf(fmaf(ay + s01.y, dn, bb.y), 0.f);
  v.z = fmaxf(fmaf(az + s23.x, dn, bb.z), 0.f);
  v.w = fmaxf(fmaf(aw + s23.y, dn, bb.w), 0.f);
  const float4* Wo4 = (const float4*)Wout;
  float4 wo = Wo4[q];
  float p = v.x*wo.x + v.y*wo.y + v.z*wo.z + v.w*wo.w;
  p += __shfl_xor(p,1,64); p += __shfl_xor(p,2,64);
  p += __shfl_xor(p,4,64); p += __shfl_xor(p,8,64);
  if (lane == 0) atomicAdd(&gsum[batch[n]], p);
}

__global__ void k_final(const float* __restrict__ gsum, const int* __restrict__ gcount,
                        const float* __restrict__ bout, float* __restrict__ out, int G){
  int g = blockIdx.x*blockDim.x + threadIdx.x;
  if (g < G){
    int c = gcount[g];
    out[g] = gsum[g]/(float)(c > 0 ? c : 1) + bout[0];
  }
}

extern "C" void kernel_launch(void* const* d_in, const int* in_sizes, int n_in,
                              void* d_out, int out_size, void* d_ws, size_t ws_size,
                              hipStream_t stream){
  const float* x    = (const float*)d_in[0];
  const int*   ei   = (const int*)d_in[1];
  const int*   batch= (const int*)d_in[2];
  const float* W1 = (const float*)d_in[3];  const float* b1 = (const float*)d_in[4];
  const float* W2 = (const float*)d_in[5];  const float* b2 = (const float*)d_in[6];
  const float* W3 = (const float*)d_in[7];  const float* b3 = (const float*)d_in[8];
  const float* W4 = (const float*)d_in[9];  const float* b4 = (const float*)d_in[10];
  const float* Wout = (const float*)d_in[11]; const float* bout = (const float*)d_in[12];
  float* out = (float*)d_out;

  const int N = in_sizes[0]/9;
  const int E = in_sizes[1]/2;
  const int G = out_size;
  const int* src = ei;        // edge_index[0]
  const int* dst = ei + E;    // edge_index[1]

  char* ws = (char*)d_ws;
  size_t off = 0;
  auto alloc = [&](size_t bytes){ void* p = ws + off; off = align256(off + bytes); return p; };
  int*   deg      = (int*)  alloc((size_t)N*4);
  int*   row_ptr  = (int*)  alloc((size_t)(N+1)*4);
  int*   csr      = (int*)  alloc((size_t)E*4);
  float* dis      = (float*)alloc((size_t)N*4);
  const int NB  = (N + 255)/256;        // 391 (< 512 required by k_scanB)
  const int NBK = (N + 127)/128;        // 782 buckets of 128 dst nodes
  const int NC  = (E + CHUNK-1)/CHUNK;  // 489 sort chunks
  int*   blockSums= (int*)  alloc((size_t)NB*4);
  int*   blockOffs= (int*)  alloc((size_t)NB*4);
  int*   hoffC    = (int*)  alloc((size_t)NC*783*4);   // per-chunk bucket offsets
  float* gsum     = (float*)alloc((size_t)G*4);
  int*   gcount   = (int*)  alloc((size_t)G*4);
  float* bufA     = (float*)alloc((size_t)N*64*4);
  h4v*   mbuf     = (h4v*)  alloc((size_t)N*64*2);   // fp16 message rows (128B)
  float* xagg     = (float*)mbuf;  // layer-1 9-feat aggregate (N*9*4 <= N*128)
  float* xs       = bufA;   // premultiplied x aliases bufA (freed by k_lin1 write)
  int*   binned   = (int*)bufA;  // E*4 = 4MB <= N*64*4; consumed by k_gather
                                 // BEFORE k_premul writes xs into the same region

  const int EN = (E > N) ? E : N;

  k_zero     <<<(N+255)/256, 256, 0, stream>>>(deg, gsum, gcount, N, G);
  k_deg      <<<(EN+255)/256, 256, 0, stream>>>(dst, batch, deg, gcount, E, N);
  k_scanA    <<<NB, 256, 0, stream>>>(deg, blockSums, N);
  k_scanB    <<<1, 512, 0, stream>>>(blockSums, blockOffs, NB);
  k_scanC    <<<NB, 256, 0, stream>>>(deg, blockOffs, row_ptr, dis, N);
  k_sortchunk<<<NC, 256, 0, stream>>>(src, dst, binned, hoffC, E);
  k_gather   <<<NBK, 256, 0, stream>>>(binned, hoffC, row_ptr, csr, N, NC);

  // layer 1: premultiply, aggregate (9 feats), then transform
  k_premul<<<(N*9+255)/256, 256, 0, stream>>>(x, dis, xs, N);
  k_agg9  <<<(N*9+255)/256, 256, 0, stream>>>(xs, dis, row_ptr, csr, xagg, N);
  k_lin1  <<<(N*64+255)/256, 256, 0, stream>>>(xagg, W1, b1, bufA, N);

  // layers 2-3: transform (with dis premult, fp16 store) then aggregate
  const float* Ws[2] = {W2, W3};
  const float* bs[2] = {b2, b3};
  for (int l = 0; l < 2; l++){
    k_lin64<<<1792, 256, 0, stream>>>(bufA, Ws[l], dis, mbuf, N);
    k_agg64<<<(N*64+255)/256, 256, 0, stream>>>(mbuf, dis, bs[l], row_ptr, csr, bufA, N);
  }

  // layer 4: transform, then aggregation fused with output projection + pool
  k_lin64<<<1792, 256, 0, stream>>>(bufA, W4, dis, mbuf, N);
  k_agg64_out<<<(N*64+255)/256, 256, 0, stream>>>(mbuf, dis, b4, Wout, batch,
                                                  row_ptr, csr, gsum, N);

  k_final<<<(G+255)/256, 256, 0, stream>>>(gsum, gcount, bout, out, G);
}

// Round 4
// 422.344 us; speedup vs baseline: 1.5977x; 1.0316x over previous
//
#include <hip/hip_runtime.h>
#include <hip/hip_fp16.h>

// GCN: 4x (gcn_conv + relu) + global mean pool + linear out.
// N=100000 nodes, E=1000000 edges, G=4096 graphs, F_IN=9, H=64.
// R1: k_agg64 MLP restructure; layer-4 agg fused with output projection.
// R2 (FAILED, 237us): global bucket-cursor scatter -- atomic contention.
// R3: scatter-free CSR build (LDS chunk sort + single-writer bucket gather).
// R4: fp16 message rows (128B).  FETCH halved (126->60MB) but dur 75->72us:
//     agg is NOT byte-bound.  R1-vs-R4 invariant = instruction/dep structure
//     => latency-chain-bound (row_ptr -> csr -> ~2 m-rounds ~ 1900cyc/node).
// R5: attack the chain, not the bytes:
//     - 8 subgroups x 8 lanes (16B/lane): 16 edges in flight per wave, one
//       m-latency round for ~90% of nodes (deg~Poisson(10)).
//     - persistent grid-stride waves w/ next-node row_ptr prefetch: row_ptr
//       link hidden under previous node's gather.
//     - 2048-block persistent launch -> full 8 blocks/CU.

static inline size_t align256(size_t x){ return (x + 255) & ~size_t(255); }

#define CHUNK 2048          // edges per sort chunk
#define NBKT  782           // ceil(100000/128) buckets of 128 dst nodes

struct __align__(8)  h4v { __half2 a, b; };        // 4 halves = 8B (lin64 store)
struct __align__(16) h8v { __half2 a, b, c, d; };  // 8 halves = 16B (agg gather)

__global__ void k_zero(int* deg, float* gsum, int* gcount, int N, int G){
  int i = blockIdx.x*blockDim.x + threadIdx.x;
  if (i < N) deg[i] = 0;
  if (i < G){ gsum[i] = 0.f; gcount[i] = 0; }
}

__global__ void k_deg(const int* __restrict__ dst, const int* __restrict__ batch,
                      int* deg, int* gcount, int E, int N){
  int i = blockIdx.x*blockDim.x + threadIdx.x;
  if (i < E) atomicAdd(&deg[dst[i]], 1);
  if (i < N) atomicAdd(&gcount[batch[i]], 1);
}

__global__ void k_scanA(const int* __restrict__ deg, int* blockSums, int N){
  __shared__ int s[256];
  int t = threadIdx.x; int i = blockIdx.x*256 + t;
  s[t] = (i < N) ? deg[i] : 0;
  __syncthreads();
  for (int off=128; off>0; off>>=1){ if (t < off) s[t] += s[t+off]; __syncthreads(); }
  if (t==0) blockSums[blockIdx.x] = s[0];
}

// single-block exclusive scan of up to 512 block sums (NB=391 here)
__global__ void k_scanB(const int* __restrict__ blockSums, int* blockOffs, int NB){
  __shared__ int s[512];
  int t = threadIdx.x;
  int v = (t < NB) ? blockSums[t] : 0;
  s[t] = v; __syncthreads();
  for (int off=1; off<512; off<<=1){
    int add = (t>=off) ? s[t-off] : 0; __syncthreads();
    s[t] += add; __syncthreads();
  }
  if (t < NB) blockOffs[t] = s[t] - v;
}

// exclusive scan -> row_ptr; also dis
__global__ void k_scanC(const int* __restrict__ deg, const int* __restrict__ blockOffs,
                        int* row_ptr, float* dis, int N){
  __shared__ int s[256];
  int t = threadIdx.x; int i = blockIdx.x*256 + t;
  int v = (i < N) ? deg[i] : 0;
  s[t] = v; __syncthreads();
  for (int off=1; off<256; off<<=1){
    int add = (t>=off) ? s[t-off] : 0; __syncthreads();
    s[t] += add; __syncthreads();
  }
  if (i < N){
    int row = blockOffs[blockIdx.x] + s[t] - v;   // exclusive
    row_ptr[i] = row;
    dis[i] = rsqrtf((float)(v + 1));              // +1 self-loop; deg>=1
    if (i == N-1) row_ptr[N] = blockOffs[blockIdx.x] + s[t];
  }
}

// pass 1: sort a 2048-edge chunk by bucket entirely in LDS, emit the sorted
// image (coalesced) + the chunk's 783-entry bucket-offset row (coalesced).
// Entry packed as (src<<7)|(dst&127); src < 2^17 fits.
__global__ __launch_bounds__(256) void k_sortchunk(
    const int* __restrict__ src, const int* __restrict__ dst,
    int* __restrict__ binned, int* __restrict__ hoffC, int E){
  __shared__ int hcnt[1024];            // 782 used; padded pow2 for scan
  __shared__ int simg[CHUNK];
  int c = blockIdx.x, t = threadIdx.x;
  int e0 = c*CHUNK;
  int cnt = E - e0; if (cnt > CHUNK) cnt = CHUNK;

  for (int i = t; i < 1024; i += 256) hcnt[i] = 0;
  __syncthreads();

  int b_[8], r_[8], v_[8];              // static-indexed (stays in VGPRs)
  #pragma unroll
  for (int j = 0; j < 8; j++){
    int i = t + j*256;
    if (i < cnt){
      int d = dst[e0+i];
      int s = src[e0+i];
      int b = d >> 7;
      b_[j] = b;
      r_[j] = atomicAdd(&hcnt[b], 1);
      v_[j] = (s << 7) | (d & 127);
    } else b_[j] = -1;
  }
  __syncthreads();

  // in-place Hillis-Steele inclusive scan of hcnt[0..1023]
  int own[4];
  #pragma unroll
  for (int j = 0; j < 4; j++) own[j] = hcnt[t + j*256];
  for (int off = 1; off < 1024; off <<= 1){
    int nv[4];
    #pragma unroll
    for (int j = 0; j < 4; j++){
      int i = t + j*256;
      nv[j] = hcnt[i] + ((i >= off) ? hcnt[i-off] : 0);
    }
    __syncthreads();
    #pragma unroll
    for (int j = 0; j < 4; j++) hcnt[t + j*256] = nv[j];
    __syncthreads();
  }
  // inclusive -> exclusive
  #pragma unroll
  for (int j = 0; j < 4; j++) hcnt[t + j*256] -= own[j];
  __syncthreads();

  // emit bucket-offset row (hcnt[782] == cnt since buckets >=782 are empty)
  for (int i = t; i < 783; i += 256) hoffC[c*783 + i] = hcnt[i];

  // place edges bucket-major in LDS
  #pragma unroll
  for (int j = 0; j < 8; j++)
    if (b_[j] >= 0) simg[hcnt[b_[j]] + r_[j]] = v_[j];
  __syncthreads();

  // coalesced stream-out of the sorted chunk image
  for (int i = t; i < cnt; i += 256) binned[e0 + i] = simg[i];
}

// pass 2: WG per bucket gathers its segments from every chunk image and writes
// its own csr region (single-writer, full-line writebacks).  Per-node order
// resolved with LDS cursors.
__global__ __launch_bounds__(256) void k_gather(
    const int* __restrict__ binned, const int* __restrict__ hoffC,
    const int* __restrict__ row_ptr,
    int* __restrict__ csr, int N, int NC){
  __shared__ int lcur[128];
  int b = blockIdx.x, t = threadIdx.x;
  int n0 = b << 7;
  int nn = N - n0; if (nn > 128) nn = 128;
  if (t < nn) lcur[t] = row_ptr[n0 + t];
  __syncthreads();
  for (int c = t; c < NC; c += 256){
    int o0 = hoffC[c*783 + b];
    int o1 = hoffC[c*783 + b + 1];
    int base = c*CHUNK;
    for (int k = o0; k < o1; k++){
      int v = binned[base + k];
      int pos = atomicAdd(&lcur[v & 127], 1);
      csr[pos] = v >> 7;
    }
  }
}

// xs[n] = x[n] * dis[n]  (premultiply so the gather loop has one load per edge)
__global__ void k_premul(const float* __restrict__ x, const float* __restrict__ dis,
                         float* __restrict__ xs, int N){
  int i = blockIdx.x*blockDim.x + threadIdx.x;
  if (i < N*9) xs[i] = x[i]*dis[i/9];
}

// layer-1 aggregation over xs (9 features): thread per (node, feature), unroll-4 MLP
__global__ void k_agg9(const float* __restrict__ xs, const float* __restrict__ dis,
                       const int* __restrict__ row_ptr, const int* __restrict__ csr,
                       float* __restrict__ xagg, int N){
  int tid = blockIdx.x*blockDim.x + threadIdx.x;
  if (tid >= N*9) return;
  int n = tid/9, f = tid - n*9;
  float dn = dis[n];
  int s0 = row_ptr[n], s1 = row_ptr[n+1];
  float a0 = xs[tid];                 // self-loop term (x[n]*dis[n])
  float a1 = 0.f, a2 = 0.f, a3 = 0.f;
  int j = s0;
  for (; j + 3 < s1; j += 4){
    int e0 = csr[j], e1 = csr[j+1], e2 = csr[j+2], e3 = csr[j+3];
    a0 += xs[e0*9+f];
    a1 += xs[e1*9+f];
    a2 += xs[e2*9+f];
    a3 += xs[e3*9+f];
  }
  for (; j < s1; j++) a0 += xs[csr[j]*9+f];
  xagg[tid] = ((a0+a1)+(a2+a3))*dn;
}

// h1 = relu(xagg @ W1 + b1)   (9 -> 64)
__global__ void k_lin1(const float* __restrict__ xagg, const float* __restrict__ W1,
                       const float* __restrict__ b1, float* __restrict__ h, int N){
  __shared__ float Wl[576];
  __shared__ float bl[64];
  int t = threadIdx.x;
  for (int i = t; i < 576; i += 256) Wl[i] = W1[i];
  if (t < 64) bl[t] = b1[t];
  __syncthreads();
  int tid = blockIdx.x*256 + t;
  int n = tid >> 6, f = tid & 63;
  if (n >= N) return;
  float acc = bl[f];
  #pragma unroll
  for (int k = 0; k < 9; k++) acc = fmaf(xagg[n*9+k], Wl[k*64+f], acc);
  h[tid] = fmaxf(acc, 0.f);
}

// m[n] = fp16( dis[n] * (h[n] @ W) )   (64 -> 64); 16-node tiles, 4 outs/thread
__global__ __launch_bounds__(256) void k_lin64(
    const float* __restrict__ h, const float* __restrict__ W,
    const float* __restrict__ dis, h4v* __restrict__ m, int N){
  __shared__ __align__(16) float Wl[64*64];
  __shared__ float hl[16*65];          // +1 pad: conflict-free broadcast reads
  int t = threadIdx.x;
  for (int i = t; i < 4096; i += 256) Wl[i] = W[i];
  int tiles = (N + 15) >> 4;
  int nl = t >> 4, q = t & 15;
  const float4* W4 = (const float4*)Wl;
  for (int tile = blockIdx.x; tile < tiles; tile += gridDim.x){
    int n0 = tile << 4;
    __syncthreads();
    #pragma unroll
    for (int j = 0; j < 4; j++){
      int idx = t + j*256;                       // 0..1023 over 16 nodes x 64 feats
      int node = n0 + (idx >> 6);
      float v = (node < N) ? h[n0*64 + idx] : 0.f;
      hl[(idx>>6)*65 + (idx&63)] = v;
    }
    __syncthreads();
    int node = n0 + nl;
    if (node < N){
      float4 acc = {0.f,0.f,0.f,0.f};
      #pragma unroll
      for (int k = 0; k < 64; k++){
        float hv = hl[nl*65 + k];
        float4 w = W4[k*16 + q];
        acc.x = fmaf(hv, w.x, acc.x);
        acc.y = fmaf(hv, w.y, acc.y);
        acc.z = fmaf(hv, w.z, acc.z);
        acc.w = fmaf(hv, w.w, acc.w);
      }
      float s = dis[node];
      h4v o;
      o.a = __floats2half2_rn(acc.x*s, acc.y*s);
      o.b = __floats2half2_rn(acc.z*s, acc.w*s);
      m[n0*16 + t] = o;                 // 8B/thread, coalesced
    }
  }
}

#define ACC8(a)  do{ float2 t_;                                    \
  t_ = __half22float2((a).a); acc0 += t_.x; acc1 += t_.y;          \
  t_ = __half22float2((a).b); acc2 += t_.x; acc3 += t_.y;          \
  t_ = __half22float2((a).c); acc4 += t_.x; acc5 += t_.y;          \
  t_ = __half22float2((a).d); acc6 += t_.x; acc7 += t_.y; }while(0)

#define RED3(v)  do{ v += __shfl_xor(v, 8,64);                     \
                     v += __shfl_xor(v,16,64);                     \
                     v += __shfl_xor(v,32,64); }while(0)

// h'[n] = relu(dis[n]*(m[n] + sum_nbr m[s]) + b)
// wave = 1 node; 8 subgroups x 8 lanes; subgroup gathers one 128B fp16 row
// (16B/lane) => 16 edges in ONE latency round for ~90% of nodes.  Persistent
// grid-stride waves prefetch the NEXT node's row_ptr during the gather.
__global__ __launch_bounds__(256) void k_agg64(
    const h8v* __restrict__ m, const float* __restrict__ dis,
    const float* __restrict__ b,
    const int* __restrict__ row_ptr, const int* __restrict__ csr,
    float* __restrict__ h, int N, int nwaves){
  int lane = threadIdx.x & 63;
  int sub = lane >> 3, q2 = lane & 7;
  int n = (blockIdx.x*blockDim.x + threadIdx.x) >> 6;
  if (n >= N) return;
  int rp0 = row_ptr[n], rp1 = row_ptr[n+1];
  const float4* b4 = (const float4*)b;
  while (true){
    int nn = n + nwaves;
    int np0 = 0, np1 = 0;
    if (nn < N){ np0 = row_ptr[nn]; np1 = row_ptr[nn+1]; }   // prefetch (indep)
    h8v sf = m[(size_t)n*8 + q2];                            // self row (indep)
    float dn = dis[n];
    float acc0=0.f,acc1=0.f,acc2=0.f,acc3=0.f,acc4=0.f,acc5=0.f,acc6=0.f,acc7=0.f;
    int s1 = rp1;
    int j0 = rp0 + sub, j1 = rp0 + 8 + sub;
    if (j0 < s1){ h8v a = m[(size_t)csr[j0]*8 + q2]; ACC8(a); }
    if (j1 < s1){ h8v a = m[(size_t)csr[j1]*8 + q2]; ACC8(a); }
    for (int j = rp0 + 16 + sub; j < s1; j += 8){            // rare (deg>16)
      h8v a = m[(size_t)csr[j]*8 + q2]; ACC8(a);
    }
    RED3(acc0); RED3(acc1); RED3(acc2); RED3(acc3);
    RED3(acc4); RED3(acc5); RED3(acc6); RED3(acc7);
    float2 s01 = __half22float2(sf.a), s23 = __half22float2(sf.b);
    float2 s45 = __half22float2(sf.c), s67 = __half22float2(sf.d);
    float4 bb0 = b4[q2*2], bb1 = b4[q2*2+1];
    float r0 = fmaxf(fmaf(acc0 + s01.x, dn, bb0.x), 0.f);
    float r1 = fmaxf(fmaf(acc1 + s01.y, dn, bb0.y), 0.f);
    float r2 = fmaxf(fmaf(acc2 + s23.x, dn, bb0.z), 0.f);
    float r3 = fmaxf(fmaf(acc3 + s23.y, dn, bb0.w), 0.f);
    float r4 = fmaxf(fmaf(acc4 + s45.x, dn, bb1.x), 0.f);
    float r5 = fmaxf(fmaf(acc5 + s45.y, dn, bb1.y), 0.f);
    float r6 = fmaxf(fmaf(acc6 + s67.x, dn, bb1.z), 0.f);
    float r7 = fmaxf(fmaf(acc7 + s67.y, dn, bb1.w), 0.f);
    float4* hrow = (float4*)(h + (size_t)n*64);
    if (sub == 0) hrow[q2*2]   = make_float4(r0,r1,r2,r3);
    if (sub == 1) hrow[q2*2+1] = make_float4(r4,r5,r6,r7);
    if (nn >= N) break;
    n = nn; rp0 = np0; rp1 = np1;
  }
}

// layer-4 aggregation fused with output projection: per-node dot(h4, Wout)
// -> wave reduce -> atomic segment add.  No h store at all.
__global__ __launch_bounds__(256) void k_agg64_out(
    const h8v* __restrict__ m, const float* __restrict__ dis,
    const float* __restrict__ b, const float* __restrict__ Wout,
    const int* __restrict__ batch,
    const int* __restrict__ row_ptr, const int* __restrict__ csr,
    float* gsum, int N, int nwaves){
  int lane = threadIdx.x & 63;
  int sub = lane >> 3, q2 = lane & 7;
  int n = (blockIdx.x*blockDim.x + threadIdx.x) >> 6;
  if (n >= N) return;
  int rp0 = row_ptr[n], rp1 = row_ptr[n+1];
  const float4* b4 = (const float4*)b;
  const float4* wo4 = (const float4*)Wout;
  while (true){
    int nn = n + nwaves;
    int np0 = 0, np1 = 0;
    if (nn < N){ np0 = row_ptr[nn]; np1 = row_ptr[nn+1]; }   // prefetch (indep)
    h8v sf = m[(size_t)n*8 + q2];                            // self row (indep)
    float dn = dis[n];
    int bg = batch[n];
    float acc0=0.f,acc1=0.f,acc2=0.f,acc3=0.f,acc4=0.f,acc5=0.f,acc6=0.f,acc7=0.f;
    int s1 = rp1;
    int j0 = rp0 + sub, j1 = rp0 + 8 + sub;
    if (j0 < s1){ h8v a = m[(size_t)csr[j0]*8 + q2]; ACC8(a); }
    if (j1 < s1){ h8v a = m[(size_t)csr[j1]*8 + q2]; ACC8(a); }
    for (int j = rp0 + 16 + sub; j < s1; j += 8){            // rare (deg>16)
      h8v a = m[(size_t)csr[j]*8 + q2]; ACC8(a);
    }
    RED3(acc0); RED3(acc1); RED3(acc2); RED3(acc3);
    RED3(acc4); RED3(acc5); RED3(acc6); RED3(acc7);
    float2 s01 = __half22float2(sf.a), s23 = __half22float2(sf.b);
    float2 s45 = __half22float2(sf.c), s67 = __half22float2(sf.d);
    float4 bb0 = b4[q2*2], bb1 = b4[q2*2+1];
    float4 w0 = wo4[q2*2], w1 = wo4[q2*2+1];
    float r0 = fmaxf(fmaf(acc0 + s01.x, dn, bb0.x), 0.f);
    float r1 = fmaxf(fmaf(acc1 + s01.y, dn, bb0.y), 0.f);
    float r2 = fmaxf(fmaf(acc2 + s23.x, dn, bb0.z), 0.f);
    float r3 = fmaxf(fmaf(acc3 + s23.y, dn, bb0.w), 0.f);
    float r4 = fmaxf(fmaf(acc4 + s45.x, dn, bb1.x), 0.f);
    float r5 = fmaxf(fmaf(acc5 + s45.y, dn, bb1.y), 0.f);
    float r6 = fmaxf(fmaf(acc6 + s67.x, dn, bb1.z), 0.f);
    float r7 = fmaxf(fmaf(acc7 + s67.y, dn, bb1.w), 0.f);
    float p = r0*w0.x + r1*w0.y + r2*w0.z + r3*w0.w
            + r4*w1.x + r5*w1.y + r6*w1.z + r7*w1.w;
    p += __shfl_xor(p,1,64); p += __shfl_xor(p,2,64); p += __shfl_xor(p,4,64);
    if (lane == 0) atomicAdd(&gsum[bg], p);
    if (nn >= N) break;
    n = nn; rp0 = np0; rp1 = np1;
  }
}

__global__ void k_final(const float* __restrict__ gsum, const int* __restrict__ gcount,
                        const float* __restrict__ bout, float* __restrict__ out, int G){
  int g = blockIdx.x*blockDim.x + threadIdx.x;
  if (g < G){
    int c = gcount[g];
    out[g] = gsum[g]/(float)(c > 0 ? c : 1) + bout[0];
  }
}

extern "C" void kernel_launch(void* const* d_in, const int* in_sizes, int n_in,
                              void* d_out, int out_size, void* d_ws, size_t ws_size,
                              hipStream_t stream){
  const float* x    = (const float*)d_in[0];
  const int*   ei   = (const int*)d_in[1];
  const int*   batch= (const int*)d_in[2];
  const float* W1 = (const float*)d_in[3];  const float* b1 = (const float*)d_in[4];
  const float* W2 = (const float*)d_in[5];  const float* b2 = (const float*)d_in[6];
  const float* W3 = (const float*)d_in[7];  const float* b3 = (const float*)d_in[8];
  const float* W4 = (const float*)d_in[9];  const float* b4 = (const float*)d_in[10];
  const float* Wout = (const float*)d_in[11]; const float* bout = (const float*)d_in[12];
  float* out = (float*)d_out;

  const int N = in_sizes[0]/9;
  const int E = in_sizes[1]/2;
  const int G = out_size;
  const int* src = ei;        // edge_index[0]
  const int* dst = ei + E;    // edge_index[1]

  char* ws = (char*)d_ws;
  size_t off = 0;
  auto alloc = [&](size_t bytes){ void* p = ws + off; off = align256(off + bytes); return p; };
  int*   deg      = (int*)  alloc((size_t)N*4);
  int*   row_ptr  = (int*)  alloc((size_t)(N+1)*4);
  int*   csr      = (int*)  alloc((size_t)E*4);
  float* dis      = (float*)alloc((size_t)N*4);
  const int NB  = (N + 255)/256;        // 391 (< 512 required by k_scanB)
  const int NBK = (N + 127)/128;        // 782 buckets of 128 dst nodes
  const int NC  = (E + CHUNK-1)/CHUNK;  // 489 sort chunks
  int*   blockSums= (int*)  alloc((size_t)NB*4);
  int*   blockOffs= (int*)  alloc((size_t)NB*4);
  int*   hoffC    = (int*)  alloc((size_t)NC*783*4);   // per-chunk bucket offsets
  float* gsum     = (float*)alloc((size_t)G*4);
  int*   gcount   = (int*)  alloc((size_t)G*4);
  float* bufA     = (float*)alloc((size_t)N*64*4);
  h4v*   mbuf     = (h4v*)  alloc((size_t)N*64*2);   // fp16 message rows (128B)
  float* xagg     = (float*)mbuf;  // layer-1 9-feat aggregate (N*9*4 <= N*128)
  float* xs       = bufA;   // premultiplied x aliases bufA (freed by k_lin1 write)
  int*   binned   = (int*)bufA;  // E*4 = 4MB <= N*64*4; consumed by k_gather
                                 // BEFORE k_premul writes xs into the same region

  const int EN = (E > N) ? E : N;
  const int AGG_BLOCKS = 2048;             // persistent: 8 blocks/CU on 256 CUs
  const int AGG_WAVES  = AGG_BLOCKS*4;     // 4 waves/block, 1 node each per step

  k_zero     <<<(N+255)/256, 256, 0, stream>>>(deg, gsum, gcount, N, G);
  k_deg      <<<(EN+255)/256, 256, 0, stream>>>(dst, batch, deg, gcount, E, N);
  k_scanA    <<<NB, 256, 0, stream>>>(deg, blockSums, N);
  k_scanB    <<<1, 512, 0, stream>>>(blockSums, blockOffs, NB);
  k_scanC    <<<NB, 256, 0, stream>>>(deg, blockOffs, row_ptr, dis, N);
  k_sortchunk<<<NC, 256, 0, stream>>>(src, dst, binned, hoffC, E);
  k_gather   <<<NBK, 256, 0, stream>>>(binned, hoffC, row_ptr, csr, N, NC);

  // layer 1: premultiply, aggregate (9 feats), then transform
  k_premul<<<(N*9+255)/256, 256, 0, stream>>>(x, dis, xs, N);
  k_agg9  <<<(N*9+255)/256, 256, 0, stream>>>(xs, dis, row_ptr, csr, xagg, N);
  k_lin1  <<<(N*64+255)/256, 256, 0, stream>>>(xagg, W1, b1, bufA, N);

  // layers 2-3: transform (with dis premult, fp16 store) then aggregate
  const float* Ws[2] = {W2, W3};
  const float* bs[2] = {b2, b3};
  for (int l = 0; l < 2; l++){
    k_lin64<<<1792, 256, 0, stream>>>(bufA, Ws[l], dis, mbuf, N);
    k_agg64<<<AGG_BLOCKS, 256, 0, stream>>>((const h8v*)mbuf, dis, bs[l],
                                            row_ptr, csr, bufA, N, AGG_WAVES);
  }

  // layer 4: transform, then aggregation fused with output projection + pool
  k_lin64<<<1792, 256, 0, stream>>>(bufA, W4, dis, mbuf, N);
  k_agg64_out<<<AGG_BLOCKS, 256, 0, stream>>>((const h8v*)mbuf, dis, b4, Wout, batch,
                                              row_ptr, csr, gsum, N, AGG_WAVES);

  k_final<<<(G+255)/256, 256, 0, stream>>>(gsum, gcount, bout, out, G);
}